// Round 3
// baseline (43.880 us; speedup 1.0000x reference)
//
#include <hip/hip_runtime.h>
#include <cmath>

#define NP 64    // patients
#define NM 16    // mats per patient
#define NA 512   // input_size (row length)
#define NB 128   // rows per mat
#define H1 256
#define H2 256
#define NC 32

__device__ __forceinline__ float sigmoid_(float x) {
    return 1.0f / (1.0f + __expf(-x));
}

__device__ __forceinline__ float dot4(float4 a, float4 b, float acc) {
    acc = fmaf(a.x, b.x, acc);
    acc = fmaf(a.y, b.y, acc);
    acc = fmaf(a.z, b.z, acc);
    acc = fmaf(a.w, b.w, acc);
    return acc;
}

// ---------------- K1: gather + fc1 ----------------
// grid 64 = 8 patient-tiles x 8 output-tiles. Block: 8 patients x 32 outputs.
// Only x[p, NM-1, :, NB-1] matters. W1 slice per block = 32 rows = 64 KB (L1-resident,
// shared by all 4 waves). Patient rows staged in LDS (broadcast reads).
extern "C" __global__ __launch_bounds__(256)
void k1_fc1(const float* __restrict__ x,
            const float* __restrict__ W1, const float* __restrict__ b1,
            float* __restrict__ h1out)
{
    __shared__ float rows[8][NA];   // 16 KB

    const int pt = blockIdx.x >> 3;   // patient tile 0..7
    const int ot = blockIdx.x & 7;    // output tile 0..7
    const int t  = threadIdx.x;

    // gather 8 rows (strided: element stride NB floats)
    for (int idx = t; idx < 8 * NA; idx += 256) {
        const int pl = idx >> 9;          // local patient
        const int a  = idx & (NA - 1);
        const size_t gi = ((((size_t)(pt * 8 + pl) * NM + (NM - 1)) * NA + a) * NB) + (NB - 1);
        rows[pl][a] = x[gi];
    }
    __syncthreads();

    const int pl = t >> 5;            // 0..7
    const int ol = t & 31;            // 0..31
    const int o  = ot * 32 + ol;

    const float4* w = (const float4*)(W1 + (size_t)o * NA);
    const float4* r = (const float4*)rows[pl];

    float a0 = 0.f, a1 = 0.f, a2 = 0.f, a3 = 0.f;
    #pragma unroll 8
    for (int k = 0; k < NA / 4; k += 4) {
        a0 = dot4(w[k + 0], r[k + 0], a0);
        a1 = dot4(w[k + 1], r[k + 1], a1);
        a2 = dot4(w[k + 2], r[k + 2], a2);
        a3 = dot4(w[k + 3], r[k + 3], a3);
    }
    const float v = (a0 + a1) + (a2 + a3) + b1[o];
    h1out[(size_t)(pt * 8 + pl) * H1 + o] = fmaxf(v, 0.f);
}

// ---------------- K2: LSTM gates (i,g,o) -> h ----------------
// grid 64 j-tiles x 4 j each. Thread: (j = jt*4 + t>>6, p = t&63).
// Weight addresses are wave-uniform (one broadcast line per load); h1 reads are
// 64 lines/instr but L1-reused across the 4 waves.
extern "C" __global__ __launch_bounds__(256)
void k2_lstm(const float* __restrict__ h1in,
             const float* __restrict__ W_ih,
             const float* __restrict__ b_ih, const float* __restrict__ b_hh,
             float* __restrict__ hout)
{
    const int t = threadIdx.x;
    const int j = blockIdx.x * 4 + (t >> 6);
    const int p = t & 63;

    const float4* wi = (const float4*)(W_ih + (size_t)j * H1);
    const float4* wg = (const float4*)(W_ih + (size_t)(2 * H2 + j) * H1);
    const float4* wo = (const float4*)(W_ih + (size_t)(3 * H2 + j) * H1);
    const float4* hv = (const float4*)(h1in + (size_t)p * H1);

    float i0 = 0.f, i1 = 0.f, g0 = 0.f, g1 = 0.f, o0 = 0.f, o1 = 0.f;
    #pragma unroll 8
    for (int k = 0; k < H1 / 4; k += 2) {
        float4 h4a = hv[k], h4b = hv[k + 1];
        i0 = dot4(wi[k], h4a, i0);  i1 = dot4(wi[k + 1], h4b, i1);
        g0 = dot4(wg[k], h4a, g0);  g1 = dot4(wg[k + 1], h4b, g1);
        o0 = dot4(wo[k], h4a, o0);  o1 = dot4(wo[k + 1], h4b, o1);
    }
    const float ai = i0 + i1 + b_ih[j]            + b_hh[j];
    const float ag = g0 + g1 + b_ih[2 * H2 + j]   + b_hh[2 * H2 + j];
    const float ao = o0 + o1 + b_ih[3 * H2 + j]   + b_hh[3 * H2 + j];

    const float c = sigmoid_(ai) * tanhf(ag);
    const float h = sigmoid_(ao) * tanhf(c);
    hout[(size_t)p * H2 + j] = fmaxf(h, 0.f);
}

// ---------------- K3: fc3 + softmax ----------------
// grid 64 (one block per patient). 8 lanes per class, shuffle reduce, wave softmax.
extern "C" __global__ __launch_bounds__(256)
void k3_fc3(const float* __restrict__ hin,
            const float* __restrict__ W3, const float* __restrict__ b3,
            float* __restrict__ out)
{
    __shared__ float logits[NC];

    const int p = blockIdx.x;
    const int t = threadIdx.x;

    const int g = t >> 3;   // class 0..31
    const int l = t & 7;

    const float4* w  = (const float4*)(W3 + (size_t)g * H2);
    const float4* hv = (const float4*)(hin + (size_t)p * H2);
    float acc = 0.f;
    #pragma unroll
    for (int j = 0; j < 8; ++j)
        acc = dot4(w[l + 8 * j], hv[l + 8 * j], acc);

    acc += __shfl_down(acc, 4, 64);
    acc += __shfl_down(acc, 2, 64);
    acc += __shfl_down(acc, 1, 64);
    if (l == 0) logits[g] = acc + b3[g];
    __syncthreads();

    if (t < NC) {
        float v = logits[t];
        float m = v;
        #pragma unroll
        for (int off = 16; off; off >>= 1) m = fmaxf(m, __shfl_xor(m, off, 64));
        float e = __expf(v - m);
        float s = e;
        #pragma unroll
        for (int off = 16; off; off >>= 1) s += __shfl_xor(s, off, 64);
        out[p * NC + t] = e / s;
    }
}

extern "C" void kernel_launch(void* const* d_in, const int* in_sizes, int n_in,
                              void* d_out, int out_size, void* d_ws, size_t ws_size,
                              hipStream_t stream) {
    const float* x    = (const float*)d_in[0];
    const float* W1   = (const float*)d_in[1];
    const float* b1   = (const float*)d_in[2];
    const float* W_ih = (const float*)d_in[3];
    // d_in[4] = W_hh: unused (h0 = 0 kills the recurrent term)
    const float* b_ih = (const float*)d_in[5];
    const float* b_hh = (const float*)d_in[6];
    const float* W3   = (const float*)d_in[7];
    const float* b3   = (const float*)d_in[8];
    float* out = (float*)d_out;

    float* h1 = (float*)d_ws;                       // 64*256 f32 = 64 KB
    float* h  = h1 + (size_t)NP * H1;               // next 64 KB

    hipLaunchKernelGGL(k1_fc1, dim3(64), dim3(256), 0, stream, x, W1, b1, h1);
    hipLaunchKernelGGL(k2_lstm, dim3(64), dim3(256), 0, stream, h1, W_ih, b_ih, b_hh, h);
    hipLaunchKernelGGL(k3_fc3, dim3(64), dim3(256), 0, stream, h, W3, b3, out);
}

// Round 4
// 42.933 us; speedup vs baseline: 1.0221x; 1.0221x over previous
//
#include <hip/hip_runtime.h>
#include <cmath>

#define NP 64    // patients
#define NM 16    // mats per patient
#define NA 512   // input_size (row length)
#define NB 128   // rows per mat
#define H1 256
#define H2 256
#define NC 32

__device__ __forceinline__ float sigmoid_(float x) {
    return 1.0f / (1.0f + __expf(-x));
}

__device__ __forceinline__ float dot4(float4 a, float4 b, float acc) {
    acc = fmaf(a.x, b.x, acc);
    acc = fmaf(a.y, b.y, acc);
    acc = fmaf(a.z, b.z, acc);
    acc = fmaf(a.w, b.w, acc);
    return acc;
}

// Single fused kernel: one block per patient (grid=64, block=256).
// Only x[p, NM-1, :, NB-1] reaches the output (reference keeps outs[:, -1, :]),
// and h0=c0=0 kills the W_hh term and the forget gate.
extern "C" __global__ __launch_bounds__(256)
void rnn_fused(const float* __restrict__ x,
               const float* __restrict__ W1, const float* __restrict__ b1,
               const float* __restrict__ W_ih,
               const float* __restrict__ b_ih, const float* __restrict__ b_hh,
               const float* __restrict__ W3, const float* __restrict__ b3,
               float* __restrict__ out)
{
    __shared__ float row[NA];    // 2 KB
    __shared__ float h1s[H1];    // 1 KB
    __shared__ float hs[H2];     // 1 KB
    __shared__ float logits[NC];

    const int p = blockIdx.x;
    const int t = threadIdx.x;

    // ---- gather the single relevant row: x[p, NM-1, a, NB-1], stride NB ----
    const size_t abase = ((size_t)p * NM + (NM - 1)) * NA;
    for (int a = t; a < NA; a += 256)
        row[a] = x[(abase + a) * NB + (NB - 1)];
    __syncthreads();

    // ---- fc1 + ReLU: h1[t] = relu(W1[t,:] . row + b1[t]), 4-way ILP ----
    {
        const float4* w = (const float4*)(W1 + (size_t)t * NA);
        const float4* r = (const float4*)row;
        float a0 = 0.f, a1 = 0.f, a2 = 0.f, a3 = 0.f;
        #pragma unroll 8
        for (int k = 0; k < NA / 4; k += 4) {
            a0 = dot4(w[k + 0], r[k + 0], a0);
            a1 = dot4(w[k + 1], r[k + 1], a1);
            a2 = dot4(w[k + 2], r[k + 2], a2);
            a3 = dot4(w[k + 3], r[k + 3], a3);
        }
        h1s[t] = fmaxf((a0 + a1) + (a2 + a3) + b1[t], 0.f);
    }
    __syncthreads();

    // ---- 1-step LSTM, h0=c0=0: gates i,g,o (f unused), 6 accumulators ----
    {
        const float4* wi = (const float4*)(W_ih + (size_t)t * H1);
        const float4* wg = (const float4*)(W_ih + (size_t)(2 * H2 + t) * H1);
        const float4* wo = (const float4*)(W_ih + (size_t)(3 * H2 + t) * H1);
        const float4* hv = (const float4*)h1s;
        float i0 = 0.f, i1 = 0.f, g0 = 0.f, g1 = 0.f, o0 = 0.f, o1 = 0.f;
        #pragma unroll 8
        for (int k = 0; k < H1 / 4; k += 2) {
            float4 h4a = hv[k], h4b = hv[k + 1];
            i0 = dot4(wi[k], h4a, i0);  i1 = dot4(wi[k + 1], h4b, i1);
            g0 = dot4(wg[k], h4a, g0);  g1 = dot4(wg[k + 1], h4b, g1);
            o0 = dot4(wo[k], h4a, o0);  o1 = dot4(wo[k + 1], h4b, o1);
        }
        const float ai = i0 + i1 + b_ih[t]          + b_hh[t];
        const float ag = g0 + g1 + b_ih[2 * H2 + t] + b_hh[2 * H2 + t];
        const float ao = o0 + o1 + b_ih[3 * H2 + t] + b_hh[3 * H2 + t];
        const float c = sigmoid_(ai) * tanhf(ag);
        const float h = sigmoid_(ao) * tanhf(c);
        hs[t] = fmaxf(h, 0.f);
    }
    __syncthreads();

    // ---- fc3: 32 classes, 8 lanes per class, shuffle reduce ----
    {
        const int g = t >> 3;   // class 0..31
        const int l = t & 7;
        const float4* w  = (const float4*)(W3 + (size_t)g * H2);
        const float4* hv = (const float4*)hs;
        float acc = 0.f;
        #pragma unroll
        for (int j = 0; j < 8; ++j)
            acc = dot4(w[l + 8 * j], hv[l + 8 * j], acc);
        acc += __shfl_down(acc, 4, 64);
        acc += __shfl_down(acc, 2, 64);
        acc += __shfl_down(acc, 1, 64);
        if (l == 0) logits[g] = acc + b3[g];
    }
    __syncthreads();

    // ---- softmax over 32 classes (lanes 0..31 of wave 0) ----
    if (t < NC) {
        float v = logits[t];
        float m = v;
        #pragma unroll
        for (int off = 16; off; off >>= 1) m = fmaxf(m, __shfl_xor(m, off, 64));
        float e = __expf(v - m);
        float s = e;
        #pragma unroll
        for (int off = 16; off; off >>= 1) s += __shfl_xor(s, off, 64);
        out[p * NC + t] = e / s;
    }
}

extern "C" void kernel_launch(void* const* d_in, const int* in_sizes, int n_in,
                              void* d_out, int out_size, void* d_ws, size_t ws_size,
                              hipStream_t stream) {
    const float* x    = (const float*)d_in[0];
    const float* W1   = (const float*)d_in[1];
    const float* b1   = (const float*)d_in[2];
    const float* W_ih = (const float*)d_in[3];
    // d_in[4] = W_hh: unused (h0 = 0 kills the recurrent term)
    const float* b_ih = (const float*)d_in[5];
    const float* b_hh = (const float*)d_in[6];
    const float* W3   = (const float*)d_in[7];
    const float* b3   = (const float*)d_in[8];
    float* out = (float*)d_out;

    hipLaunchKernelGGL(rnn_fused, dim3(NP), dim3(256), 0, stream,
                       x, W1, b1, W_ih, b_ih, b_hh, W3, b3, out);
}